// Round 1
// baseline (252.336 us; speedup 1.0000x reference)
//
#include <hip/hip_runtime.h>

// B=64, S=512, D=256, VOCAB=50000, NC=10, N_STEPS=10 (h=0.1), BN eval.
// Strategy: RK4 on linear RHS == affine map per step; collapse 10 steps into
// z_final = z0 @ P10 + ctot  (P10 = M^10, M = 4th-order Taylor of exp(hA), A=W^T).
// Conv k as GEMM with K=k*256 using shifted LDS reads of the X tile.
// All big GEMMs in bf16 MFMA 16x16x32; threshold is ~2% relative -> safe.
//
// This revision: k_main B-tile staging is double-buffered (T14 async-STAGE
// split: issue next-stage loads -> compute current -> ds_write -> ONE barrier),
// halving barriers and hiding the L2 load latency under the MFMA block.
// k_mm gets 4 accumulators + 16-load window; repack/memset merged.

typedef short bf16x8 __attribute__((ext_vector_type(8)));
typedef float f32x4 __attribute__((ext_vector_type(4)));

__device__ __forceinline__ unsigned short f2bf(float f) {
  unsigned u = __float_as_uint(f);
  u += 0x7FFFu + ((u >> 16) & 1u);   // RNE; inputs are normal floats
  return (unsigned short)(u >> 16);
}

// ---------------- prep: small 256x256 fp32 linear algebra ----------------

__global__ void k_hA(const float* __restrict__ W, float* __restrict__ hA) {
  int i = blockIdx.x, j = threadIdx.x;
  // A = W^T, scaled by h=0.1:  hA[i][j] = 0.1 * W[j][i]
  hA[i * 256 + j] = 0.1f * W[j * 256 + i];
}

// blocks 0..255: C = A @ Bm (256x256). block 256 (if va): vout = va @ Bm + vadd
__global__ void k_mm(const float* __restrict__ A, const float* __restrict__ Bm,
                     float* __restrict__ C,
                     const float* __restrict__ va, const float* __restrict__ vadd,
                     float* __restrict__ vout) {
  __shared__ float arow[256];
  int j = threadIdx.x;
  if (blockIdx.x < 256) {
    int i = blockIdx.x;
    arow[j] = A[i * 256 + j];
    __syncthreads();
    float a0 = 0.f, a1 = 0.f, a2 = 0.f, a3 = 0.f;
#pragma unroll 4
    for (int k = 0; k < 256; k += 4) {
      a0 = fmaf(arow[k + 0], Bm[(k + 0) * 256 + j], a0);
      a1 = fmaf(arow[k + 1], Bm[(k + 1) * 256 + j], a1);
      a2 = fmaf(arow[k + 2], Bm[(k + 2) * 256 + j], a2);
      a3 = fmaf(arow[k + 3], Bm[(k + 3) * 256 + j], a3);
    }
    C[i * 256 + j] = (a0 + a1) + (a2 + a3);
  } else {
    if (va == nullptr) return;
    arow[j] = va[j];
    __syncthreads();
    float a0 = vadd ? vadd[j] : 0.f, a1 = 0.f, a2 = 0.f, a3 = 0.f;
#pragma unroll 4
    for (int k = 0; k < 256; k += 4) {
      a0 = fmaf(arow[k + 0], Bm[(k + 0) * 256 + j], a0);
      a1 = fmaf(arow[k + 1], Bm[(k + 1) * 256 + j], a1);
      a2 = fmaf(arow[k + 2], Bm[(k + 2) * 256 + j], a2);
      a3 = fmaf(arow[k + 3], Bm[(k + 3) * 256 + j], a3);
    }
    vout[j] = (a0 + a1) + (a2 + a3);
  }
}

// blocks 0..255: M = I + hA + A2/2 + A3/6 + A4/24
// block 256: c1 = 0.1 * b @ (I + hA/2 + A2/6 + A3/24)
__global__ void k_buildM(const float* __restrict__ hA, const float* __restrict__ A2,
                         const float* __restrict__ A3, const float* __restrict__ A4,
                         float* __restrict__ Mm,
                         const float* __restrict__ bvec, float* __restrict__ c1) {
  __shared__ float bs[256];
  int j = threadIdx.x;
  if (blockIdx.x < 256) {
    int i = blockIdx.x;
    int e = i * 256 + j;
    float I = (i == j) ? 1.f : 0.f;
    Mm[e] = I + hA[e] + A2[e] * (1.f / 2.f) + A3[e] * (1.f / 6.f) + A4[e] * (1.f / 24.f);
  } else {
    bs[j] = bvec[j];
    __syncthreads();
    float acc = bs[j];  // identity term
#pragma unroll 8
    for (int k = 0; k < 256; ++k) {
      int e = k * 256 + j;
      float q = hA[e] * 0.5f + A2[e] * (1.f / 6.f) + A3[e] * (1.f / 24.f);
      acc = fmaf(bs[k], q, acc);
    }
    c1[j] = 0.1f * acc;
  }
}

// ---------------- repack weights into MFMA B-fragment order ----------------
// slice layout (32768 bf16 each): [kc(8)][quad(4)][o(128)][q8(8)]
// element (kd = kc*32+quad*8+q8, o) == B[kd][o]
// slices 0..2: conv3 j=0..2; 3..6: conv4; 7..11: conv5; 12..13: node o-halves.
// blocks 0..1535: conv repack. blocks 1536..1791: node repack + featbuf zero.

__global__ void k_repack(const float* __restrict__ w3, const float* __restrict__ w4,
                         const float* __restrict__ w5, const float* __restrict__ P10,
                         unsigned short* __restrict__ slab, unsigned* __restrict__ featbuf) {
  const int blk = blockIdx.x, tid = threadIdx.x;
  if (blk < 1536) {
    int e = blk * 256 + tid;  // < 12*32768
    int s = e >> 15;
    int r = e & 32767;
    int kd = r >> 7;
    int o = r & 127;
    const float* w; int k, j;
    if (s < 3)      { w = w3; k = 3; j = s; }
    else if (s < 7) { w = w4; k = 4; j = s - 3; }
    else            { w = w5; k = 5; j = s - 7; }
    float val = w[(o * 256 + kd) * k + j];   // w[o][d=kd][j], shape (128,256,k)
    int kc = kd >> 5, quad = (kd >> 3) & 3, q8 = kd & 7;
    slab[s * 32768 + ((kc * 4 + quad) * 128 + o) * 8 + q8] = f2bf(val);
  } else {
    int kd = blk - 1536, o = tid;
    float val = P10[kd * 256 + o];
    int kc = kd >> 5, quad = (kd >> 3) & 3, q8 = kd & 7;
    int s = 12 + (o >> 7);
    slab[s * 32768 + ((kc * 4 + quad) * 128 + (o & 127)) * 8 + q8] = f2bf(val);
    int fi = kd * 256 + o;
    if (fi < 64 * 640) featbuf[fi] = 0u;
  }
}

// ---------------- fused main kernel ----------------
// grid 512 = 64 batches x 8 t-chunks of 64. 256 threads = 4 waves.
// LDS: X tile 68 rows x 264 bf16 (+8 pad => 2-way-free banks, 16B-aligned rows),
//      B tile 2 x 16 KB double-buffered, staged per flat entry e=(slice,kcq).
// Wave tile: TM=4 (all 64 rows) x TN=2 (32 cols); 4 waves cover N=128.
// Per iteration: issue next-stage loads -> 16 MFMA from Bt[cur] -> epilogue at
// group ends -> ds_write Bt[cur^1] -> ONE barrier.

__global__ __launch_bounds__(256, 2) void k_main(
    const int* __restrict__ ids, const float* __restrict__ emb,
    const unsigned short* __restrict__ slab, const float* __restrict__ ctot,
    const float* __restrict__ b3, const float* __restrict__ g3, const float* __restrict__ be3,
    const float* __restrict__ b4, const float* __restrict__ g4, const float* __restrict__ be4,
    const float* __restrict__ b5, const float* __restrict__ g5, const float* __restrict__ be5,
    unsigned* __restrict__ featbuf) {
  __shared__ alignas(16) unsigned short Xt[68 * 264];
  __shared__ alignas(16) unsigned short Bt[2][8192];
  __shared__ int ids_s[68];
  const int tid = threadIdx.x;
  const int blk = blockIdx.x;
  const int b = blk >> 3;
  const int t0 = (blk & 7) * 64;
  const int lane = tid & 63;
  const int wave = tid >> 6;
  const int m15 = lane & 15;
  const int quad = lane >> 4;

  if (tid < 68) {
    int t = t0 + tid;
    ids_s[tid] = (t < 512) ? ids[b * 512 + t] : -1;
  }
  __syncthreads();

  // issue entry-0 B-stage loads first; latency hides under the X gather
  const uint4* slab4 = (const uint4*)slab;
  uint4 st0 = slab4[tid];
  uint4 st1 = slab4[tid + 256];
  uint4 st2 = slab4[tid + 512];
  uint4 st3 = slab4[tid + 768];

  // gather + fp32->bf16 X tile (rows beyond S zero-filled)
  for (int i = tid; i < 68 * 64; i += 256) {
    int row = i >> 6, s4 = i & 63;
    uint2 v = make_uint2(0u, 0u);
    int id = ids_s[row];
    if (id >= 0) {
      const float4 f = *(const float4*)(emb + (size_t)id * 256 + s4 * 4);
      v.x = (unsigned)f2bf(f.x) | ((unsigned)f2bf(f.y) << 16);
      v.y = (unsigned)f2bf(f.z) | ((unsigned)f2bf(f.w) << 16);
    }
    *(uint2*)&Xt[row * 264 + s4 * 4] = v;
  }
  {
    uint4* dst = (uint4*)Bt[0] + tid;
    dst[0] = st0; dst[256] = st1; dst[512] = st2; dst[768] = st3;
  }
  __syncthreads();  // Xt + Bt[0] ready

  f32x4 acc[4][2];
#pragma unroll
  for (int mt = 0; mt < 4; ++mt)
#pragma unroll
    for (int nt = 0; nt < 2; ++nt) acc[mt][nt] = (f32x4){0.f, 0.f, 0.f, 0.f};

  int cur = 0;
  for (int e = 0; e < 56; ++e) {
    const int slice = e >> 2;
    const int kcq = e & 3;
    // conv shift = ji within group; node slices shift 0
    const int shift = (slice < 3) ? slice
                    : (slice < 7) ? (slice - 3)
                    : (slice < 12) ? (slice - 7) : 0;

    // prefetch next stage into regs (no wait until the ds_write below)
    if (e < 55) {
      const uint4* src = slab4 + (((e + 1) >> 2) * 4096 + ((e + 1) & 3) * 1024) + tid;
      st0 = src[0]; st1 = src[256]; st2 = src[512]; st3 = src[768];
    }

    const unsigned short* Bc = Bt[cur];
#pragma unroll
    for (int kc2 = 0; kc2 < 2; ++kc2) {
      const int kd0 = (kcq * 2 + kc2) * 32 + quad * 8;
      bf16x8 af[4];
#pragma unroll
      for (int mt = 0; mt < 4; ++mt)
        af[mt] = *(const bf16x8*)&Xt[(shift + mt * 16 + m15) * 264 + kd0];
#pragma unroll
      for (int nt = 0; nt < 2; ++nt) {
        const bf16x8 bfr =
            *(const bf16x8*)&Bc[((kc2 * 4 + quad) * 128 + (wave * 2 + nt) * 16 + m15) * 8];
#pragma unroll
        for (int mt = 0; mt < 4; ++mt)
          acc[mt][nt] = __builtin_amdgcn_mfma_f32_16x16x32_bf16(af[mt], bfr, acc[mt][nt], 0, 0, 0);
      }
    }

    // epilogue at group boundaries (registers + shuffles + atomics only)
    if (kcq == 3) {
      const int g = (e == 11) ? 0 : (e == 27) ? 1 : (e == 47) ? 2
                  : (e == 51) ? 3 : (e == 55) ? 4 : -1;
      if (g >= 0) {
        if (g < 3) {
          const int kk = g + 3;
          const float* bb  = (g == 0) ? b3 : (g == 1) ? b4 : b5;
          const float* gg  = (g == 0) ? g3 : (g == 1) ? g4 : g5;
          const float* bbe = (g == 0) ? be3 : (g == 1) ? be4 : be5;
          const int off = 256 + g * 128;   // feats: [node 256][p3 128][p4 128][p5 128]
          const int tmax = 512 - kk;
#pragma unroll
          for (int nt = 0; nt < 2; ++nt) {
            const int n = (wave * 2 + nt) * 16 + m15;
            const float sc = gg[n] * 0.9999950000375f;  // g * 1/sqrt(1+1e-5)
            const float sh = fmaf(sc, bb[n], bbe[n]);
            float mx = 0.f;  // relu floor doubles as init
#pragma unroll
            for (int mt = 0; mt < 4; ++mt)
#pragma unroll
              for (int r = 0; r < 4; ++r) {
                const int t = t0 + mt * 16 + quad * 4 + r;
                const float v = fmaf(sc, acc[mt][nt][r], sh);
                if (t <= tmax) mx = fmaxf(mx, v);
              }
            mx = fmaxf(mx, __shfl_xor(mx, 16));
            mx = fmaxf(mx, __shfl_xor(mx, 32));
            if (quad == 0) atomicMax(&featbuf[b * 640 + off + n], __float_as_uint(mx));
          }
        } else {
          const int base = (g == 3) ? 0 : 128;
#pragma unroll
          for (int nt = 0; nt < 2; ++nt) {
            const int n = (wave * 2 + nt) * 16 + m15;
            const float ct = ctot[base + n];
            float mx = -3.4e38f;
#pragma unroll
            for (int mt = 0; mt < 4; ++mt)
#pragma unroll
              for (int r = 0; r < 4; ++r)
                mx = fmaxf(mx, acc[mt][nt][r] + ct);
            mx = fmaxf(mx, __shfl_xor(mx, 16));
            mx = fmaxf(mx, __shfl_xor(mx, 32));
            if (quad == 0) {
              unsigned bits = __float_as_uint(mx);
              unsigned key = (bits & 0x80000000u) ? ~bits : (bits | 0x80000000u);  // order-preserving
              atomicMax(&featbuf[b * 640 + base + n], key);
            }
          }
        }
        // reset accumulators for the next group
#pragma unroll
        for (int mt = 0; mt < 4; ++mt)
#pragma unroll
          for (int nt = 0; nt < 2; ++nt) acc[mt][nt] = (f32x4){0.f, 0.f, 0.f, 0.f};
      }
    }

    // write next stage into the other buffer (vmcnt drain lands here,
    // after ~300+ cycles of MFMA/ds_read work), then a single barrier
    if (e < 55) {
      uint4* dst = (uint4*)Bt[cur ^ 1] + tid;
      dst[0] = st0; dst[256] = st1; dst[512] = st2; dst[768] = st3;
    }
    __syncthreads();
    cur ^= 1;
  }
}

// ---------------- classifier ----------------
__global__ void k_fin(const unsigned* __restrict__ featbuf, const float* __restrict__ wc,
                      const float* __restrict__ bc, float* __restrict__ out) {
  int b = blockIdx.x, lane = threadIdx.x;  // 64 threads = 1 wave
  float p[10];
#pragma unroll
  for (int c = 0; c < 10; ++c) p[c] = 0.f;
  for (int f = lane; f < 640; f += 64) {
    unsigned u = featbuf[b * 640 + f];
    float v;
    if (f < 256) v = (u & 0x80000000u) ? __uint_as_float(u ^ 0x80000000u) : __uint_as_float(~u);
    else v = __uint_as_float(u);
#pragma unroll
    for (int c = 0; c < 10; ++c) p[c] = fmaf(v, wc[c * 640 + f], p[c]);
  }
#pragma unroll
  for (int c = 0; c < 10; ++c) {
    float s = p[c];
#pragma unroll
    for (int off = 32; off > 0; off >>= 1) s += __shfl_down(s, off);
    if (lane == 0) out[b * 10 + c] = s + bc[c];
  }
}

// ---------------- launcher ----------------
extern "C" void kernel_launch(void* const* d_in, const int* in_sizes, int n_in,
                              void* d_out, int out_size, void* d_ws, size_t ws_size,
                              hipStream_t stream) {
  (void)in_sizes; (void)n_in; (void)out_size; (void)ws_size;
  const int*   ids  = (const int*)d_in[0];
  const float* emb  = (const float*)d_in[1];
  const float* W    = (const float*)d_in[2];
  const float* bode = (const float*)d_in[3];
  const float* w3   = (const float*)d_in[4];
  const float* b3   = (const float*)d_in[5];
  const float* g3   = (const float*)d_in[6];
  const float* be3  = (const float*)d_in[7];
  const float* w4   = (const float*)d_in[8];
  const float* b4   = (const float*)d_in[9];
  const float* g4   = (const float*)d_in[10];
  const float* be4  = (const float*)d_in[11];
  const float* w5   = (const float*)d_in[12];
  const float* b5   = (const float*)d_in[13];
  const float* g5   = (const float*)d_in[14];
  const float* be5  = (const float*)d_in[15];
  const float* wc   = (const float*)d_in[16];
  const float* bc   = (const float*)d_in[17];
  float* out = (float*)d_out;

  float* wsf = (float*)d_ws;
  float* hA  = wsf;                 // 65536 floats each
  float* A2  = wsf + 65536;
  float* A3  = wsf + 131072;
  float* A4  = wsf + 196608;
  float* Mm  = wsf + 262144;
  float* P2  = wsf + 327680;
  float* P4  = wsf + 393216;
  float* P5  = wsf + 458752;
  float* P10 = wsf + 524288;
  float* c1  = wsf + 589824;
  float* c2  = c1 + 256;
  float* c4  = c1 + 512;
  float* c5  = c1 + 768;
  float* c10 = c1 + 1024;
  unsigned short* slab = (unsigned short*)(wsf + 591872);   // 14 slices * 32768 bf16
  unsigned* featbuf = (unsigned*)(slab + 14 * 32768);       // 64*640 uint keys

  hipLaunchKernelGGL(k_hA, dim3(256), dim3(256), 0, stream, W, hA);
  const float* nf = nullptr;
  hipLaunchKernelGGL(k_mm, dim3(257), dim3(256), 0, stream, hA, hA, A2, nf, nf, (float*)nullptr);
  hipLaunchKernelGGL(k_mm, dim3(257), dim3(256), 0, stream, A2, hA, A3, nf, nf, (float*)nullptr);
  hipLaunchKernelGGL(k_mm, dim3(257), dim3(256), 0, stream, A3, hA, A4, nf, nf, (float*)nullptr);
  hipLaunchKernelGGL(k_buildM, dim3(257), dim3(256), 0, stream, hA, A2, A3, A4, Mm, bode, c1);
  // affine-map composition: (P,c)_1 -> 2 -> 4 -> 5 -> 10
  hipLaunchKernelGGL(k_mm, dim3(257), dim3(256), 0, stream, Mm, Mm, P2, c1, c1, c2);
  hipLaunchKernelGGL(k_mm, dim3(257), dim3(256), 0, stream, P2, P2, P4, c2, c2, c4);
  hipLaunchKernelGGL(k_mm, dim3(257), dim3(256), 0, stream, P4, Mm, P5, c4, c1, c5);
  hipLaunchKernelGGL(k_mm, dim3(257), dim3(256), 0, stream, P5, P5, P10, c5, c5, c10);
  hipLaunchKernelGGL(k_repack, dim3(1792), dim3(256), 0, stream, w3, w4, w5, P10, slab, featbuf);
  hipLaunchKernelGGL(k_main, dim3(512), dim3(256), 0, stream,
                     ids, emb, slab, c10,
                     b3, g3, be3, b4, g4, be4, b5, g5, be5, featbuf);
  hipLaunchKernelGGL(k_fin, dim3(64), dim3(64), 0, stream, featbuf, wc, bc, out);
}